// Round 10
// baseline (248.483 us; speedup 1.0000x reference)
//
#include <hip/hip_runtime.h>

// FlowNet correlation: out[b, dy*9+dx, y, x] = (1/256) sum_c x1[b,c,y,x] * x2[b,c,y+dy-4,x+dx-4]
// B=4 C=256 H=W=128, 9x9 displacements, zero padding.
//
// Round-14 = r4 structure exact + X1 REGISTER DOUBLE-BUFFER.
// Diagnosis: r5/r7/r8/r13 prove more waves never help (r13 clean: Occ 21->29.5%,
// dur WORSE); no pipe >40% -> per-wave serial critical path. r4's VGPR_Count==64
// == exact live set at the FMA block (acc36+nf12+v12+a4): the allocator squeezed
// to the 64-reg boundary by SERIALIZING the 4 per-channel x1 loads -> 4 exposed
// L2 latencies (~1100cy) per ~3800cy chunk, per wave, unhideable at 2.25 w/SIMD.
// The original session's x1-prefetch attempt was reverted under a SPILL confound
// (launch-bounds cap), like every TLP probe. Clean retest:
//  - x1 chunk k+1 -> registers (aB) issued AFTER the barrier, consumed next
//    chunk: full compute phase of cover; x2 commit waits only its OLDER nf loads.
//  - 2x-unrolled k-loop with named aA/aB sets (static indexing, no scratch).
//  - __launch_bounds__(192, 2): VGPR cap ~256, room for ~110 live regs, no
//    spill cliff; occupancy is grid-limited (3 blk/CU) so nothing is lost.
// Kept validated: 192 thr, CC=4, RSC=48 (2.65M conflicts), gy=lane>>2
// (coalesced), XCD swizzle, x2 reg->LDS double-buffer, direct-out epilogue.

#define MD 4
constexpr int Bc = 4, Cc = 256, Hc = 128, Wc = 128;
constexpr int HW = Hc * Wc;
constexpr int TH = 16, TW = 16;
constexpr int NDY = 3;                  // dy per d-group (one per wave)
constexpr int CC = 4;                   // channels per chunk
constexpr int SROWS = TH + NDY - 1;     // 18 staged rows
constexpr int SCOLS = TW + 2 * MD;      // 24 staged cols
constexpr int RSC = 48;                 // padded row stride (dw), 48%32==16 -> clean b128
constexpr int CH_STRIDE = SROWS * RSC;  // 864 dw per channel
constexpr int BUF_DW = CC * CH_STRIDE;  // 3456 dw per buffer
constexpr int NF4 = CC * SROWS * (SCOLS / 4);  // 432 float4 staging slots
constexpr int NTHR = 192;
constexpr int NSLOT = 3;                // ceil(432/192)
constexpr int NK = Cc / CC;             // 64 chunks (even -> clean 2x unroll)

__global__ __launch_bounds__(NTHR, 2)
void corr_kernel(const float* __restrict__ x1, const float* __restrict__ x2,
                 float* __restrict__ out)
{
    __shared__ float stg[2 * BUF_DW];   // 27648 B

    const int tid  = threadIdx.x;
    const int w    = tid >> 6;          // wave id = local dy
    const int lane = tid & 63;
    const int gy   = lane >> 2;         // 0..15 tile row
    const int gx   = lane & 3;          // 0..3  col-group (4 px each)

    // ---- XCD-aware swizzle: g-siblings (same tile) differ by +8 in bid -> same XCD ----
    const int bid  = blockIdx.x;
    const int q    = bid / 24;
    const int r    = bid - q * 24;
    const int g    = r >> 3;            // d-group 0..2
    const int t    = q * 8 + (r & 7);   // tile index 0..255
    const int tx = t & 7;
    const int ty = (t >> 3) & 7;
    const int bb = t >> 6;
    const int x0 = tx * TW, y0 = ty * TH;
    const int rowbase = y0 + 3 * g - MD;   // global y of staged row 0

    // ---- hoisted staging slot descriptors (fixed per thread across chunks) ----
    int  s_goff[NSLOT], s_loff[NSLOT];
    bool s_val[NSLOT], s_act[NSLOT];
    #pragma unroll
    for (int s = 0; s < NSLOT; ++s) {
        int idx = tid + s * NTHR;
        bool active = idx < NF4;
        int i2  = active ? idx : 0;
        int cl  = i2 / (SROWS * 6);
        int rem = i2 - cl * (SROWS * 6);
        int rr  = rem / 6;
        int gc  = rem - rr * 6;
        int yy  = rowbase + rr;
        int xx  = x0 - 4 + 4 * gc;          // multiple of 4: float4 all-valid or all-invalid
        s_act[s]  = active;
        s_val[s]  = active && ((unsigned)yy < (unsigned)Hc) && ((unsigned)xx < (unsigned)(Wc - 3));
        s_goff[s] = cl * HW + yy * Wc + xx;
        s_loff[s] = cl * CH_STRIDE + rr * RSC + 4 * gc;
    }

    const float* x2b = x2 + (size_t)bb * Cc * HW;
    const float* x1b = x1 + (((size_t)bb * Cc) * Hc + (y0 + gy)) * Wc + x0 + 4 * gx;

    float acc[9][4];
    #pragma unroll
    for (int dx = 0; dx < 9; ++dx)
        #pragma unroll
        for (int p = 0; p < 4; ++p) acc[dx][p] = 0.f;

    const float4 f40 = make_float4(0.f, 0.f, 0.f, 0.f);
    float4 nf[NSLOT];
    float4 aA[CC], aB[CC];              // x1 register double-buffer

    // ---- prologue: stage x2 chunk 0 into buffer 0; load x1 chunk 0 into aA ----
    #pragma unroll
    for (int s = 0; s < NSLOT; ++s) {
        nf[s] = f40;
        if (s_val[s]) nf[s] = *(const float4*)(x2b + s_goff[s]);
    }
    #pragma unroll
    for (int s = 0; s < NSLOT; ++s)
        if (s_act[s]) *(float4*)(&stg[s_loff[s]]) = nf[s];
    #pragma unroll
    for (int cl = 0; cl < CC; ++cl)
        aA[cl] = *(const float4*)(x1b + (size_t)cl * HW);

    // one chunk iteration; acur = this chunk's x1 (in regs), anxt = next chunk's dest
    auto body = [&](int k, float4 (&acur)[CC], float4 (&anxt)[CC]) {
        const int pb = k & 1;
        // issue x2 prefetch for chunk k+1 (r4-validated placement; barrier
        // drain proven neutral r9/r10)
        if (k + 1 < NK) {
            const int gof = (k + 1) * CC * HW;
            #pragma unroll
            for (int s = 0; s < NSLOT; ++s) {
                nf[s] = f40;
                if (s_val[s]) nf[s] = *(const float4*)(x2b + gof + s_goff[s]);
            }
        }
        __syncthreads();   // chunk k's buffer fully written; prev buffer's readers done
        // issue x1 prefetch for chunk k+1 AFTER the barrier: younger than the
        // nf loads -> the x2 commit's counted vmcnt does not wait on these;
        // consumed only next chunk -> a full compute phase of latency cover.
        if (k + 1 < NK) {
            #pragma unroll
            for (int cl = 0; cl < CC; ++cl)
                anxt[cl] = *(const float4*)(x1b + ((size_t)(k + 1) * CC + cl) * HW);
        }
        // ---- compute chunk k: x1 already in registers, x2 from LDS ----
        #pragma unroll
        for (int cl = 0; cl < CC; ++cl) {
            const float* rowp = &stg[pb * BUF_DW + cl * CH_STRIDE + (gy + w) * RSC + 4 * gx];
            const float4 q0 = *(const float4*)(rowp);
            const float4 q1 = *(const float4*)(rowp + 4);
            const float4 q2 = *(const float4*)(rowp + 8);
            const float v[12] = {q0.x, q0.y, q0.z, q0.w,
                                 q1.x, q1.y, q1.z, q1.w,
                                 q2.x, q2.y, q2.z, q2.w};
            const float a[4] = {acur[cl].x, acur[cl].y, acur[cl].z, acur[cl].w};
            #pragma unroll
            for (int dx = 0; dx < 9; ++dx)
                #pragma unroll
                for (int p = 0; p < 4; ++p)
                    acc[dx][p] += a[p] * v[dx + p];
        }
        // ---- commit prefetched x2 chunk k+1 (counted wait on nf only) ----
        if (k + 1 < NK) {
            const int lb = ((k + 1) & 1) * BUF_DW;
            #pragma unroll
            for (int s = 0; s < NSLOT; ++s)
                if (s_act[s]) *(float4*)(&stg[lb + s_loff[s]]) = nf[s];
        }
    };

    for (int kk = 0; kk < NK; kk += 2) {   // NK=64: even/odd pairs, static aA/aB
        body(kk,     aA, aB);
        body(kk + 1, aB, aA);
    }

    // ---- epilogue: scale and store 9 aligned float4 per thread ----
    const float inv = 1.0f / (float)Cc;
    float* ob = out + (((size_t)bb * 81 + (3 * g + w) * 9) * Hc + (y0 + gy)) * Wc + x0 + 4 * gx;
    #pragma unroll
    for (int dx = 0; dx < 9; ++dx) {
        float4 st = make_float4(acc[dx][0] * inv, acc[dx][1] * inv,
                                acc[dx][2] * inv, acc[dx][3] * inv);
        *(float4*)(ob + dx * HW) = st;
    }
}

extern "C" void kernel_launch(void* const* d_in, const int* in_sizes, int n_in,
                              void* d_out, int out_size, void* d_ws, size_t ws_size,
                              hipStream_t stream) {
    const float* x1 = (const float*)d_in[0];
    const float* x2 = (const float*)d_in[1];
    float* out = (float*)d_out;
    dim3 grid(3 * 8 * 8 * Bc), block(NTHR);   // 768 blocks x 192 threads
    corr_kernel<<<grid, block, 0, stream>>>(x1, x2, out);
}